// Round 1
// baseline (23918.298 us; speedup 1.0000x reference)
//
#include <hip/hip_runtime.h>
#include <math.h>

#define B_  64
#define T_  800
#define U_  64
#define V_  60
#define C_  512
#define K_  10
#define KX  576   // padded hx: [0..3]=x(3)+pad, [4..63]=w(60), [64..575]=h(512)
#define G4  2048  // 4*C
#define NWG 256
#define NTH 512
#define KQ  8     // k-split across the 8 waves of a WG
#define KSL 72    // KX / KQ
#define NGRP 8
#define GRPWG 32  // WGs per barrier group (one batch-oct per group)

// ws layout (float offsets): [0..511] barrier ints (8 groups, 64-int spacing), then h double-buffer
#define WS_HG 512

__device__ __forceinline__ float sigm(float v)  { return 1.f/(1.f+__expf(-v)); }
__device__ __forceinline__ float tanhx(float v) { return 1.f - 2.f/(__expf(2.f*v)+1.f); }

__device__ __forceinline__ void group_barrier(int* bar, int grp) {
  __syncthreads();
  if (threadIdx.x == 0) {
    __threadfence();
    int* cnt = bar + grp*64;
    int* gen = cnt + 1;
    int g = __hip_atomic_load(gen, __ATOMIC_RELAXED, __HIP_MEMORY_SCOPE_AGENT);
    int v = __hip_atomic_fetch_add(cnt, 1, __ATOMIC_ACQ_REL, __HIP_MEMORY_SCOPE_AGENT);
    if (v == GRPWG-1) {
      __hip_atomic_store(cnt, 0,   __ATOMIC_RELAXED, __HIP_MEMORY_SCOPE_AGENT);
      __hip_atomic_store(gen, g+1, __ATOMIC_RELEASE, __HIP_MEMORY_SCOPE_AGENT);
    } else {
      while (__hip_atomic_load(gen, __ATOMIC_ACQUIRE, __HIP_MEMORY_SCOPE_AGENT) == g)
        __builtin_amdgcn_s_sleep(1);
    }
    __threadfence();
  }
  __syncthreads();
}

__launch_bounds__(NTH, 2)
__global__ void lstm_attn_persistent(
    const float* __restrict__ x,         // [B,T,3]
    const float* __restrict__ onehots,   // [B,U,V]
    const float* __restrict__ text_lens, // [B,1]
    const float* __restrict__ w_old,     // [B,V]
    const float* __restrict__ kappa_old, // [B,K]
    const float* __restrict__ prev_h,    // [B,C]
    const float* __restrict__ prev_c,    // [B,C]
    const float* __restrict__ W_ih,      // [4C, 63]
    const float* __restrict__ W_hh,      // [4C, C]
    const float* __restrict__ b_ih,      // [4C]
    const float* __restrict__ b_hh,      // [4C]
    const float* __restrict__ win_W,     // [30, C]
    const float* __restrict__ win_b,     // [30]
    float* __restrict__ ws,
    float* __restrict__ out)
{
  // out layout (flat, return order)
  const long OUT_WS  = 0;
  const long OUT_HS  = (long)B_*T_*V_;
  const long OUT_H   = OUT_HS + (long)B_*T_*C_;
  const long OUT_C   = OUT_H  + (long)B_*C_;
  const long OUT_W   = OUT_C  + (long)B_*C_;
  const long OUT_KAP = OUT_W  + (long)B_*V_;
  const long OUT_PHI = OUT_KAP+ (long)B_*K_;

  const int tid  = threadIdx.x;
  const int kq   = tid >> 6;        // wave id 0..7 = k-slice
  const int lane = tid & 63;
  const int bid  = blockIdx.x;
  const int grp  = bid & 7;         // batch-oct group (maps to one XCD round-robin)
  const int gblk = bid >> 3;        // 0..31: gate-column block (64 permuted cols)
  const int b0   = grp * 8;

  __shared__ __align__(16) float hx[8][KX];        // per-b extended input vector
  __shared__ __align__(16) float part[KQ][8][64];  // k-slice partials (gates, then win)
  __shared__ float p_lds[8][32];
  __shared__ float phi_lds[8][68];
  __shared__ float kap_lds[8][12];
  __shared__ float scale_lds[8];
  __shared__ int   ids_lds[8][64];

  // ---- persistent registers ----
  // permuted gate index gp = ch*4 + gate  (so the 4 gates of a channel are adjacent)
  const int gp   = gblk*64 + lane;
  const int gate = gp & 3;
  const int ch   = gp >> 2;
  const int row  = gate*C_ + ch;    // row in original [4C,*] weight matrices

  float Wreg[KSL];                  // this thread's k-slice of [W_ih | W_hh] column ops
  #pragma unroll
  for (int i = 0; i < KSL; ++i) {
    int k = kq*KSL + i;
    float v;
    if      (k < 3)  v = W_ih[row*63 + k];
    else if (k == 3) v = 0.f;
    else if (k < 64) v = W_ih[row*63 + (k-1)];
    else             v = W_hh[row*C_ + (k-64)];
    Wreg[i] = v;
  }
  float bias_r = b_ih[row] + b_hh[row];

  // window rows in regs: lanes 0..59 hold (j=lane%30, half=lane/30) 32-wide k-slice
  const int wj   = lane % 30;
  const int wh   = (lane < 60) ? (lane / 30) : 0;
  float winreg[32];
  #pragma unroll
  for (int i = 0; i < 32; ++i)
    winreg[i] = win_W[wj*C_ + kq*64 + wh*32 + i];

  // LSTM cell state: thread tid<128 owns (b = b0 + (tid>>4), ch = gblk*16 + (tid&15))
  const int ub    = tid >> 4;       // 0..7 when tid<128
  const int chloc = tid & 15;
  const int mych  = gblk*16 + chloc;
  float c_reg = 0.f;
  if (tid < 128) c_reg = prev_c[(long)(b0 + ub)*C_ + mych];

  float winb_r = (tid < 240) ? win_b[tid % 30] : 0.f;

  // ---- preamble staging ----
  for (int i = tid; i < 8*KX; i += NTH) {
    int bb = i / KX, k = i % KX;
    int b = b0 + bb;
    float v;
    if      (k < 3)  v = x[((long)b*T_ + 0)*3 + k];
    else if (k < 4)  v = 0.f;
    else if (k < 64) v = w_old[b*V_ + (k-4)];
    else             v = prev_h[(long)b*C_ + (k-64)];
    hx[bb][k] = v;
  }
  for (int i = tid; i < 8*K_; i += NTH)
    kap_lds[i/K_][i%K_] = kappa_old[(b0 + i/K_)*K_ + i%K_];
  if (tid < 8) scale_lds[tid] = (float)U_ / text_lens[b0 + tid];
  for (int i = tid; i < 8*U_; i += NTH) {          // one-hot -> char id
    int bb = i / U_, u = i % U_;
    const float* oh = onehots + ((long)(b0+bb)*U_ + u)*V_;
    int best = 0; float bv = oh[0];
    for (int vv = 1; vv < V_; ++vv) { float q = oh[vv]; if (q > bv) { bv = q; best = vv; } }
    ids_lds[bb][u] = best;
  }
  __syncthreads();

  int*   bar = (int*)ws;
  float* hg  = ws + WS_HG;          // double-buffered h [2][B][C]

  for (int t = 0; t < T_; ++t) {
    // ---- phase 1: gates GEMM (k-split over waves; h/w/x broadcast from LDS) ----
    float acc[8];
    #pragma unroll
    for (int bb = 0; bb < 8; ++bb) acc[bb] = (kq == 0) ? bias_r : 0.f;
    #pragma unroll
    for (int bb = 0; bb < 8; ++bb) {
      const float* hxb = &hx[bb][kq*KSL];
      float a = acc[bb];
      #pragma unroll
      for (int i4 = 0; i4 < KSL/4; ++i4) {
        float4 h4 = *(const float4*)(hxb + i4*4);
        a = fmaf(Wreg[i4*4+0], h4.x, a);
        a = fmaf(Wreg[i4*4+1], h4.y, a);
        a = fmaf(Wreg[i4*4+2], h4.z, a);
        a = fmaf(Wreg[i4*4+3], h4.w, a);
      }
      acc[bb] = a;
    }
    #pragma unroll
    for (int bb = 0; bb < 8; ++bb) part[kq][bb][lane] = acc[bb];
    __syncthreads();

    // ---- phase 2: reduce k-slices + LSTM cell update (tid<128) ----
    if (tid < 128) {
      float4 s = make_float4(0.f, 0.f, 0.f, 0.f);
      #pragma unroll
      for (int q = 0; q < KQ; ++q) {
        float4 v = *(const float4*)&part[q][ub][chloc*4];
        s.x += v.x; s.y += v.y; s.z += v.z; s.w += v.w;
      }
      float ig = sigm(s.x), fg = sigm(s.y), gg = tanhx(s.z), og = sigm(s.w);
      float c = fg*c_reg + ig*gg;
      c_reg = c;
      float h = og * tanhx(c);
      int b = b0 + ub;
      hg[(long)(t&1)*B_*C_ + (long)b*C_ + mych] = h;
      out[OUT_HS + ((long)b*T_ + t)*C_ + mych] = h;
      if (t == T_-1) {
        out[OUT_H + (long)b*C_ + mych] = h;
        out[OUT_C + (long)b*C_ + mych] = c;
      }
    }
    group_barrier(bar, grp);

    // ---- phase 3: stage new h (all 512 ch, from the group's 32 WGs) into hx ----
    {
      const float* src = hg + (long)(t&1)*B_*C_;
      for (int i = tid; i < 8*(C_/4); i += NTH) {
        int bb = i >> 7, k = (i & 127) * 4;
        float4 v = *(const float4*)(src + (long)(b0+bb)*C_ + k);
        *(float4*)&hx[bb][64+k] = v;
      }
    }
    __syncthreads();

    // ---- phase 4: window projection partials (lanes 0..59) ----
    #pragma unroll
    for (int bb = 0; bb < 8; ++bb) {
      const float* hb = &hx[bb][64 + kq*64 + wh*32];
      float a = 0.f;
      #pragma unroll
      for (int i4 = 0; i4 < 8; ++i4) {
        float4 h4 = *(const float4*)(hb + i4*4);
        a = fmaf(winreg[i4*4+0], h4.x, a);
        a = fmaf(winreg[i4*4+1], h4.y, a);
        a = fmaf(winreg[i4*4+2], h4.z, a);
        a = fmaf(winreg[i4*4+3], h4.w, a);
      }
      if (lane < 60) part[kq][bb][lane] = a;
    }
    __syncthreads();

    // ---- phase 5: finish p = exp(h@winW^T + winb); update kappa ----
    if (tid < 240) {
      int bb = tid / 30, j = tid % 30;
      float s = 0.f;
      #pragma unroll
      for (int q = 0; q < KQ; ++q) s += part[q][bb][j] + part[q][bb][30+j];
      float p = __expf(s + winb_r);
      p_lds[bb][j] = p;
      if (j >= 20) {
        float nk = kap_lds[bb][j-20] + p;
        kap_lds[bb][j-20] = nk;
        if (t == T_-1 && gblk == 0) out[OUT_KAP + (b0+bb)*K_ + (j-20)] = nk;
      }
    }
    __syncthreads();

    // ---- phase 6: phi[u] over u=0..64 ----
    for (int i = tid; i < 8*65; i += NTH) {
      int bb = i / 65, u = i % 65;
      float s = 0.f;
      float uf = (float)u;
      #pragma unroll
      for (int k = 0; k < K_; ++k) {
        float d = kap_lds[bb][k] - uf;
        s += p_lds[bb][k] * __expf(-p_lds[bb][10+k]*d*d);
      }
      s *= scale_lds[bb];
      phi_lds[bb][u] = s;
      if (t == T_-1 && gblk == 0) out[OUT_PHI + (b0+bb)*65 + u] = s;
    }
    __syncthreads();

    // ---- phase 7: w[v] = sum_u phi[u]*onehot  (via char ids); stage x(t+1) ----
    if (tid < 480) {
      int bb = tid / 60, v = tid % 60;
      float s = 0.f;
      #pragma unroll
      for (int u = 0; u < U_; ++u)
        s += (ids_lds[bb][u] == v) ? phi_lds[bb][u] : 0.f;
      hx[bb][4+v] = s;
      if (gblk == 0) {
        out[OUT_WS + ((long)(b0+bb)*T_ + t)*V_ + v] = s;
        if (t == T_-1) out[OUT_W + (b0+bb)*V_ + v] = s;
      }
    } else if (tid < 512) {
      int i = tid - 480, bb = i >> 2, k = i & 3;
      int tn = t + 1;
      hx[bb][k] = (k < 3 && tn < T_) ? x[((long)(b0+bb)*T_ + tn)*3 + k] : 0.f;
    }
    __syncthreads();
  }
}

extern "C" void kernel_launch(void* const* d_in, const int* in_sizes, int n_in,
                              void* d_out, int out_size, void* d_ws, size_t ws_size,
                              hipStream_t stream) {
  const float* x         = (const float*)d_in[0];
  const float* onehots   = (const float*)d_in[1];
  const float* text_lens = (const float*)d_in[2];
  const float* w_old     = (const float*)d_in[3];
  const float* kappa_old = (const float*)d_in[4];
  const float* prev_h    = (const float*)d_in[5];
  const float* prev_c    = (const float*)d_in[6];
  const float* W_ih      = (const float*)d_in[7];
  const float* W_hh      = (const float*)d_in[8];
  const float* b_ih      = (const float*)d_in[9];
  const float* b_hh      = (const float*)d_in[10];
  const float* win_W     = (const float*)d_in[11];
  const float* win_b     = (const float*)d_in[12];
  float* ws  = (float*)d_ws;
  float* out = (float*)d_out;

  // zero barrier state (replayed at the head of every graph replay)
  hipMemsetAsync(d_ws, 0, 2048, stream);

  lstm_attn_persistent<<<NWG, NTH, 0, stream>>>(
      x, onehots, text_lens, w_old, kappa_old, prev_h, prev_c,
      W_ih, W_hh, b_ih, b_hh, win_W, win_b, ws, out);
}

// Round 2
// 10010.512 us; speedup vs baseline: 2.3893x; 2.3893x over previous
//
#include <hip/hip_runtime.h>
#include <math.h>

#define B_  64
#define T_  800
#define U_  64
#define V_  60
#define C_  512
#define K_  10
#define KX  576   // padded hx: [0..3]=x(3)+pad, [4..63]=w(60), [64..575]=h(512)
#define NWG 256
#define NTH 512
#define KQ  8     // k-split across the 8 waves of a WG
#define KSL 72    // KX / KQ
#define GRPWG 32  // WGs per barrier group (one batch-oct per group)

// ws layout: [0 .. 16KB) arrival flags (8 grp x 32 wg, spaced 64B)
//            [16KB ...)  h double-buffer [2][B][C] floats
#define WS_HG 4096   // float offset

__device__ __forceinline__ float sigm(float v)  { return 1.f/(1.f+__expf(-v)); }
__device__ __forceinline__ float tanhx(float v) { return 1.f - 2.f/(__expf(2.f*v)+1.f); }

__launch_bounds__(NTH, 2)
__global__ void lstm_attn_persistent(
    const float* __restrict__ x,         // [B,T,3]
    const float* __restrict__ onehots,   // [B,U,V]
    const float* __restrict__ text_lens, // [B,1]
    const float* __restrict__ w_old,     // [B,V]
    const float* __restrict__ kappa_old, // [B,K]
    const float* __restrict__ prev_h,    // [B,C]
    const float* __restrict__ prev_c,    // [B,C]
    const float* __restrict__ W_ih,      // [4C, 63]
    const float* __restrict__ W_hh,      // [4C, C]
    const float* __restrict__ b_ih,      // [4C]
    const float* __restrict__ b_hh,      // [4C]
    const float* __restrict__ win_W,     // [30, C]
    const float* __restrict__ win_b,     // [30]
    float* __restrict__ ws,
    float* __restrict__ out)
{
  // out layout (flat, return order)
  const long OUT_WS  = 0;
  const long OUT_HS  = (long)B_*T_*V_;
  const long OUT_H   = OUT_HS + (long)B_*T_*C_;
  const long OUT_C   = OUT_H  + (long)B_*C_;
  const long OUT_W   = OUT_C  + (long)B_*C_;
  const long OUT_KAP = OUT_W  + (long)B_*V_;
  const long OUT_PHI = OUT_KAP+ (long)B_*K_;

  const int tid  = threadIdx.x;
  const int kq   = tid >> 6;        // wave id 0..7 = k-slice
  const int lane = tid & 63;
  const int bid  = blockIdx.x;
  const int grp  = bid & 7;         // batch-oct group
  const int gblk = bid >> 3;        // 0..31: gate-column block (64 permuted cols)
  const int b0   = grp * 8;

  __shared__ __align__(16) float hx[8][KX];        // per-b extended input vector
  __shared__ __align__(16) float part[KQ][8][68];  // k-slice partials (+4 pad: kills 8-way bank conflict)
  __shared__ float p_lds[8][32];
  __shared__ float phi_lds[8][68];
  __shared__ float kap_lds[8][12];
  __shared__ float scale_lds[8];
  __shared__ int   ids_lds[8][64];

  // ---- persistent registers ----
  // permuted gate index gp = ch*4 + gate  (so the 4 gates of a channel are adjacent)
  const int gp   = gblk*64 + lane;
  const int gate = gp & 3;
  const int ch   = gp >> 2;
  const int row  = gate*C_ + ch;    // row in original [4C,*] weight matrices

  float Wreg[KSL];                  // this thread's k-slice of [W_ih | W_hh]
  #pragma unroll
  for (int i = 0; i < KSL; ++i) {
    int k = kq*KSL + i;
    float v;
    if      (k < 3)  v = W_ih[row*63 + k];
    else if (k == 3) v = 0.f;
    else if (k < 64) v = W_ih[row*63 + (k-1)];
    else             v = W_hh[row*C_ + (k-64)];
    Wreg[i] = v;
  }
  float bias_r = b_ih[row] + b_hh[row];

  // window rows in regs: lanes 0..59 hold (j=lane%30, half=lane/30) 32-wide k-slice
  const int wj   = lane % 30;
  const int wh   = (lane < 60) ? (lane / 30) : 0;
  float winreg[32];
  #pragma unroll
  for (int i = 0; i < 32; ++i)
    winreg[i] = win_W[wj*C_ + kq*64 + wh*32 + i];

  // LSTM cell state: thread tid<128 owns (b = b0 + (tid>>4), ch = gblk*16 + (tid&15))
  const int ub    = tid >> 4;       // 0..7 when tid<128
  const int chloc = tid & 15;
  const int mych  = gblk*16 + chloc;
  float c_reg = 0.f;
  if (tid < 128) c_reg = prev_c[(long)(b0 + ub)*C_ + mych];

  float winb_r = (tid < 240) ? win_b[tid % 30] : 0.f;

  // ---- preamble staging ----
  for (int i = tid; i < 8*KX; i += NTH) {
    int bb = i / KX, k = i % KX;
    int b = b0 + bb;
    float v;
    if      (k < 3)  v = x[((long)b*T_ + 0)*3 + k];
    else if (k < 4)  v = 0.f;
    else if (k < 64) v = w_old[b*V_ + (k-4)];
    else             v = prev_h[(long)b*C_ + (k-64)];
    hx[bb][k] = v;
  }
  for (int i = tid; i < 8*K_; i += NTH)
    kap_lds[i/K_][i%K_] = kappa_old[(b0 + i/K_)*K_ + i%K_];
  if (tid < 8) scale_lds[tid] = (float)U_ / text_lens[b0 + tid];
  for (int i = tid; i < 8*U_; i += NTH) {          // one-hot -> char id
    int bb = i / U_, u = i % U_;
    const float* oh = onehots + ((long)(b0+bb)*U_ + u)*V_;
    int best = 0; float bv = oh[0];
    for (int vv = 1; vv < V_; ++vv) { float q = oh[vv]; if (q > bv) { bv = q; best = vv; } }
    ids_lds[bb][u] = best;
  }
  __syncthreads();

  int*   flags = (int*)ws;          // [(grp*32+wg)*16]
  float* hg    = ws + WS_HG;        // double-buffered h [2][B][C]

  for (int t = 0; t < T_; ++t) {
    // ---- phase 1: gates GEMM (k-split over waves; h/w/x broadcast from LDS) ----
    float acc[8];
    #pragma unroll
    for (int bb = 0; bb < 8; ++bb) acc[bb] = (kq == 0) ? bias_r : 0.f;
    #pragma unroll
    for (int bb = 0; bb < 8; ++bb) {
      const float* hxb = &hx[bb][kq*KSL];
      float a = acc[bb];
      #pragma unroll
      for (int i4 = 0; i4 < KSL/4; ++i4) {
        float4 h4 = *(const float4*)(hxb + i4*4);
        a = fmaf(Wreg[i4*4+0], h4.x, a);
        a = fmaf(Wreg[i4*4+1], h4.y, a);
        a = fmaf(Wreg[i4*4+2], h4.z, a);
        a = fmaf(Wreg[i4*4+3], h4.w, a);
      }
      acc[bb] = a;
    }
    #pragma unroll
    for (int bb = 0; bb < 8; ++bb) part[kq][bb][lane] = acc[bb];
    __syncthreads();

    // ---- phase 2: reduce k-slices + LSTM cell update (tid<128) ----
    if (tid < 128) {
      float4 s = make_float4(0.f, 0.f, 0.f, 0.f);
      #pragma unroll
      for (int q = 0; q < KQ; ++q) {
        float4 v = *(const float4*)&part[q][ub][chloc*4];
        s.x += v.x; s.y += v.y; s.z += v.z; s.w += v.w;
      }
      float ig = sigm(s.x), fg = sigm(s.y), gg = tanhx(s.z), og = sigm(s.w);
      float c = fg*c_reg + ig*gg;
      c_reg = c;
      float h = og * tanhx(c);
      int b = b0 + ub;
      // publish h to MALL (L1/L2 bypass) — visible to any XCD, no cache-wide ops
      __hip_atomic_store(&hg[(long)(t&1)*B_*C_ + (long)b*C_ + mych], h,
                         __ATOMIC_RELAXED, __HIP_MEMORY_SCOPE_AGENT);
      out[OUT_HS + ((long)b*T_ + t)*C_ + mych] = h;
      if (t == T_-1) {
        out[OUT_H + (long)b*C_ + mych] = h;
        out[OUT_C + (long)b*C_ + mych] = c;
      }
    }

    // ---- fence-free group barrier: monotonic flags via relaxed agent atomics ----
    asm volatile("s_waitcnt vmcnt(0)" ::: "memory");  // h stores retired (sc1 => at MALL)
    __syncthreads();
    if (tid == 0)
      __hip_atomic_store(&flags[(grp*GRPWG + gblk)*16], t+1,
                         __ATOMIC_RELAXED, __HIP_MEMORY_SCOPE_AGENT);
    {
      const int slot = (grp*GRPWG + (lane & 31))*16;
      while (true) {
        int v = __hip_atomic_load(&flags[slot], __ATOMIC_RELAXED, __HIP_MEMORY_SCOPE_AGENT);
        if (__all(v >= t+1)) break;
      }
    }
    __builtin_amdgcn_sched_barrier(0);

    // ---- phase 3: load new h (all 512 ch of 8 batches) from MALL into hx ----
    {
      const unsigned long long* src =
          (const unsigned long long*)(hg + (long)(t&1)*B_*C_);
      for (int i = tid; i < 8*(C_/2); i += NTH) {     // 4 x 8B loads per thread
        int bb = i >> 8, k = i & 255;
        unsigned long long v = __hip_atomic_load(&src[(long)(b0+bb)*(C_/2) + k],
                                                 __ATOMIC_RELAXED, __HIP_MEMORY_SCOPE_AGENT);
        *(unsigned long long*)&hx[bb][64 + 2*k] = v;
      }
    }
    __syncthreads();

    // ---- phase 4: window projection partials (lanes 0..59) ----
    #pragma unroll
    for (int bb = 0; bb < 8; ++bb) {
      const float* hb = &hx[bb][64 + kq*64 + wh*32];
      float a = 0.f;
      #pragma unroll
      for (int i4 = 0; i4 < 8; ++i4) {
        float4 h4 = *(const float4*)(hb + i4*4);
        a = fmaf(winreg[i4*4+0], h4.x, a);
        a = fmaf(winreg[i4*4+1], h4.y, a);
        a = fmaf(winreg[i4*4+2], h4.z, a);
        a = fmaf(winreg[i4*4+3], h4.w, a);
      }
      if (lane < 60) part[kq][bb][lane] = a;
    }
    __syncthreads();

    // ---- phase 5: finish p = exp(h@winW^T + winb); update kappa ----
    if (tid < 240) {
      int bb = tid / 30, j = tid % 30;
      float s = 0.f;
      #pragma unroll
      for (int q = 0; q < KQ; ++q) s += part[q][bb][j] + part[q][bb][30+j];
      float p = __expf(s + winb_r);
      p_lds[bb][j] = p;
      if (j >= 20) {
        float nk = kap_lds[bb][j-20] + p;
        kap_lds[bb][j-20] = nk;
        if (t == T_-1 && gblk == 0) out[OUT_KAP + (b0+bb)*K_ + (j-20)] = nk;
      }
    }
    __syncthreads();

    // ---- phase 6: phi[u] over u=0..64 ----
    for (int i = tid; i < 8*65; i += NTH) {
      int bb = i / 65, u = i % 65;
      float s = 0.f;
      float uf = (float)u;
      #pragma unroll
      for (int k = 0; k < K_; ++k) {
        float d = kap_lds[bb][k] - uf;
        s += p_lds[bb][k] * __expf(-p_lds[bb][10+k]*d*d);
      }
      s *= scale_lds[bb];
      phi_lds[bb][u] = s;
      if (t == T_-1 && gblk == 0) out[OUT_PHI + (b0+bb)*65 + u] = s;
    }
    __syncthreads();

    // ---- phase 7: w[v] = sum_u phi[u]*onehot (via char ids); stage x(t+1) ----
    if (tid < 480) {
      int bb = tid / 60, v = tid % 60;
      float s = 0.f;
      #pragma unroll
      for (int u = 0; u < U_; ++u)
        s += (ids_lds[bb][u] == v) ? phi_lds[bb][u] : 0.f;
      hx[bb][4+v] = s;
      if (gblk == 0) {
        out[OUT_WS + ((long)(b0+bb)*T_ + t)*V_ + v] = s;
        if (t == T_-1) out[OUT_W + (b0+bb)*V_ + v] = s;
      }
    } else if (tid < 512) {
      int i = tid - 480, bb = i >> 2, k = i & 3;
      int tn = t + 1;
      hx[bb][k] = (k < 3 && tn < T_) ? x[((long)(b0+bb)*T_ + tn)*3 + k] : 0.f;
    }
    __syncthreads();
  }
}

extern "C" void kernel_launch(void* const* d_in, const int* in_sizes, int n_in,
                              void* d_out, int out_size, void* d_ws, size_t ws_size,
                              hipStream_t stream) {
  const float* x         = (const float*)d_in[0];
  const float* onehots   = (const float*)d_in[1];
  const float* text_lens = (const float*)d_in[2];
  const float* w_old     = (const float*)d_in[3];
  const float* kappa_old = (const float*)d_in[4];
  const float* prev_h    = (const float*)d_in[5];
  const float* prev_c    = (const float*)d_in[6];
  const float* W_ih      = (const float*)d_in[7];
  const float* W_hh      = (const float*)d_in[8];
  const float* b_ih      = (const float*)d_in[9];
  const float* b_hh      = (const float*)d_in[10];
  const float* win_W     = (const float*)d_in[11];
  const float* win_b     = (const float*)d_in[12];
  float* ws  = (float*)d_ws;
  float* out = (float*)d_out;

  // zero barrier flags (replayed at the head of every graph replay)
  hipMemsetAsync(d_ws, 0, 16384, stream);

  lstm_attn_persistent<<<NWG, NTH, 0, stream>>>(
      x, onehots, text_lens, w_old, kappa_old, prev_h, prev_c,
      W_ih, W_hh, b_ih, b_hh, win_W, win_b, ws, out);
}

// Round 3
// 5754.365 us; speedup vs baseline: 4.1565x; 1.7396x over previous
//
#include <hip/hip_runtime.h>
#include <math.h>

#define B_  64
#define T_  800
#define U_  64
#define V_  60
#define C_  512
#define K_  10
#define KX  576   // padded hx: [0..3]=x(3)+pad, [4..63]=w(60), [64..575]=h(512)
#define NWG 256
#define NTH 512
#define KQ  8     // k-split across the 8 waves of a WG
#define KSL 72    // KX / KQ
#define GRPWG 32  // WGs per barrier group (one batch-oct per group)

// ws layout: [0 .. 4KB) packed flags: flags[grp*32 + wg] (one 128B line per group)
//            [4KB ...)  h double-buffer [2][B][C] floats
#define WS_HG 1024   // float offset

__device__ __forceinline__ float sigm(float v)  { return 1.f/(1.f+__expf(-v)); }
__device__ __forceinline__ float tanhx(float v) { return 1.f - 2.f/(__expf(2.f*v)+1.f); }

__launch_bounds__(NTH, 2)
__global__ void lstm_attn_persistent(
    const float* __restrict__ x,         // [B,T,3]
    const float* __restrict__ onehots,   // [B,U,V]
    const float* __restrict__ text_lens, // [B,1]
    const float* __restrict__ w_old,     // [B,V]
    const float* __restrict__ kappa_old, // [B,K]
    const float* __restrict__ prev_h,    // [B,C]
    const float* __restrict__ prev_c,    // [B,C]
    const float* __restrict__ W_ih,      // [4C, 63]
    const float* __restrict__ W_hh,      // [4C, C]
    const float* __restrict__ b_ih,      // [4C]
    const float* __restrict__ b_hh,      // [4C]
    const float* __restrict__ win_W,     // [30, C]
    const float* __restrict__ win_b,     // [30]
    float* __restrict__ ws,
    float* __restrict__ out)
{
  // out layout (flat, return order)
  const long OUT_WS  = 0;
  const long OUT_HS  = (long)B_*T_*V_;
  const long OUT_H   = OUT_HS + (long)B_*T_*C_;
  const long OUT_C   = OUT_H  + (long)B_*C_;
  const long OUT_W   = OUT_C  + (long)B_*C_;
  const long OUT_KAP = OUT_W  + (long)B_*V_;
  const long OUT_PHI = OUT_KAP+ (long)B_*K_;

  const int tid  = threadIdx.x;
  const int kq   = tid >> 6;        // wave id 0..7 = k-slice
  const int lane = tid & 63;
  const int bid  = blockIdx.x;
  const int grp  = bid & 7;         // batch-oct group
  const int gblk = bid >> 3;        // 0..31: gate-column block (64 permuted cols)
  const int b0   = grp * 8;

  __shared__ __align__(16) float hx[8][KX];        // per-b extended input vector
  __shared__ __align__(16) float part[KQ][8][68];  // k-slice partials (padded)
  __shared__ float p_lds[8][32];
  __shared__ float kap_lds[8][12];
  __shared__ float scale_lds[8];
  __shared__ int   ids_lds[8][64];

  // ---- persistent registers ----
  // permuted gate index gp = ch*4 + gate (4 gates of a channel adjacent)
  const int gp   = gblk*64 + lane;
  const int gate = gp & 3;
  const int ch   = gp >> 2;
  const int row  = gate*C_ + ch;    // row in original [4C,*] weight matrices

  float Wreg[KSL];                  // this thread's k-slice of [W_ih | W_hh]
  #pragma unroll
  for (int i = 0; i < KSL; ++i) {
    int k = kq*KSL + i;
    float v;
    if      (k < 3)  v = W_ih[row*63 + k];
    else if (k == 3) v = 0.f;
    else if (k < 64) v = W_ih[row*63 + (k-1)];
    else             v = W_hh[row*C_ + (k-64)];
    Wreg[i] = v;
  }
  float bias_r = b_ih[row] + b_hh[row];

  // window rows in regs: lanes 0..59 hold (j=lane%30, half=lane/30) 32-wide k-slice
  const int wj   = lane % 30;
  const int wh   = (lane < 60) ? (lane / 30) : 0;
  float winreg[32];
  #pragma unroll
  for (int i = 0; i < 32; ++i)
    winreg[i] = win_W[wj*C_ + kq*64 + wh*32 + i];

  // LSTM cell state: thread tid<128 owns (b = b0 + (tid>>4), ch = gblk*16 + (tid&15))
  const int ub    = tid >> 4;       // 0..7 when tid<128
  const int chloc = tid & 15;
  const int mych  = gblk*16 + chloc;
  float c_reg = 0.f;
  if (tid < 128) c_reg = prev_c[(long)(b0 + ub)*C_ + mych];

  float winb_r = (tid < 240) ? win_b[tid % 30] : 0.f;

  // ---- preamble staging ----
  for (int i = tid; i < 8*KX; i += NTH) {
    int bb = i / KX, k = i % KX;
    int b = b0 + bb;
    float v;
    if      (k < 3)  v = x[((long)b*T_ + 0)*3 + k];
    else if (k < 4)  v = 0.f;
    else if (k < 64) v = w_old[b*V_ + (k-4)];
    else             v = prev_h[(long)b*C_ + (k-64)];
    hx[bb][k] = v;
  }
  for (int i = tid; i < 8*K_; i += NTH)
    kap_lds[i/K_][i%K_] = kappa_old[(b0 + i/K_)*K_ + i%K_];
  if (tid < 8) scale_lds[tid] = (float)U_ / text_lens[b0 + tid];
  for (int i = tid; i < 8*U_; i += NTH) {          // one-hot -> char id
    int bb = i / U_, u = i % U_;
    const float* oh = onehots + ((long)(b0+bb)*U_ + u)*V_;
    int best = 0; float bv = oh[0];
    for (int vv = 1; vv < V_; ++vv) { float q = oh[vv]; if (q > bv) { bv = q; best = vv; } }
    ids_lds[bb][u] = best;
  }
  __syncthreads();

  int*   flags = (int*)ws;          // packed: flags[grp*32 + wg]
  float* hg    = ws + WS_HG;        // double-buffered h [2][B][C]

  for (int t = 0; t < T_; ++t) {
    // ---- A: gates GEMM (k-split over waves; hx broadcast from LDS) ----
    float acc[8];
    #pragma unroll
    for (int bb = 0; bb < 8; ++bb) acc[bb] = (kq == 0) ? bias_r : 0.f;
    #pragma unroll
    for (int bb = 0; bb < 8; ++bb) {
      const float* hxb = &hx[bb][kq*KSL];
      float a = acc[bb];
      #pragma unroll
      for (int i4 = 0; i4 < KSL/4; ++i4) {
        float4 h4 = *(const float4*)(hxb + i4*4);
        a = fmaf(Wreg[i4*4+0], h4.x, a);
        a = fmaf(Wreg[i4*4+1], h4.y, a);
        a = fmaf(Wreg[i4*4+2], h4.z, a);
        a = fmaf(Wreg[i4*4+3], h4.w, a);
      }
      acc[bb] = a;
    }
    #pragma unroll
    for (int bb = 0; bb < 8; ++bb) part[kq][bb][lane] = acc[bb];
    __syncthreads();   // B

    // ---- C: cell update (tid<128)  |  zero w-slots + stage x(t+1) (tid>=128) ----
    if (tid < 128) {
      float4 s = make_float4(0.f, 0.f, 0.f, 0.f);
      #pragma unroll
      for (int q = 0; q < KQ; ++q) {
        float4 v = *(const float4*)&part[q][ub][chloc*4];
        s.x += v.x; s.y += v.y; s.z += v.z; s.w += v.w;
      }
      float ig = sigm(s.x), fg = sigm(s.y), gg = tanhx(s.z), og = sigm(s.w);
      float c = fg*c_reg + ig*gg;
      c_reg = c;
      float h = og * tanhx(c);
      int b = b0 + ub;
      // publish h via MALL (L1/L2 bypass): visible to any XCD, no cache-wide ops
      __hip_atomic_store(&hg[(long)(t&1)*B_*C_ + (long)b*C_ + mych], h,
                         __ATOMIC_RELAXED, __HIP_MEMORY_SCOPE_AGENT);
      out[OUT_HS + ((long)b*T_ + t)*C_ + mych] = h;
      if (t == T_-1) {
        out[OUT_H + (long)b*C_ + mych] = h;
        out[OUT_C + (long)b*C_ + mych] = c;
      }
    } else if (tid < 480) {
      // zero the 480 w-slots (next consumer: this step's scatter, after 2 syncs)
      int s0 = tid - 128;
      hx[s0/60][4 + s0%60] = 0.f;
      if (s0 < 128) { int s1 = s0 + 352; hx[s1/60][4 + s1%60] = 0.f; }
    } else {
      int i = tid - 480, bb = i >> 2, k = i & 3;
      int tn = t + 1;
      hx[bb][k] = (k < 3 && tn < T_) ? x[((long)(b0+bb)*T_ + tn)*3 + k] : 0.f;
    }
    __syncthreads();   // D: drains hg stores (vmcnt(0) embedded in barrier)

    // ---- E: flag + single-wave poll ----
    if (tid == 0)
      __hip_atomic_store(&flags[grp*GRPWG + gblk], t+1,
                         __ATOMIC_RELAXED, __HIP_MEMORY_SCOPE_AGENT);
    if (kq == 0) {
      const int slot = grp*GRPWG + (lane & 31);
      while (true) {
        int v = __hip_atomic_load(&flags[slot], __ATOMIC_RELAXED, __HIP_MEMORY_SCOPE_AGENT);
        if (__all((lane < 32) ? (v >= t+1) : true)) break;
      }
    }
    __syncthreads();   // F: release
    __builtin_amdgcn_sched_barrier(0);

    // ---- G: gather new h (8 batches x 512 ch) from MALL into hx ----
    {
      const unsigned long long* src =
          (const unsigned long long*)(hg + (long)(t&1)*B_*C_);
      for (int i = tid; i < 8*(C_/2); i += NTH) {   // 4 x 8B loads per thread
        int bb = i >> 8, k = i & 255;
        unsigned long long v = __hip_atomic_load(&src[(long)(b0+bb)*(C_/2) + k],
                                                 __ATOMIC_RELAXED, __HIP_MEMORY_SCOPE_AGENT);
        *(unsigned long long*)&hx[bb][64 + 2*k] = v;
      }
    }
    __syncthreads();   // H

    // ---- I: window projection partials (lanes 0..59) ----
    #pragma unroll
    for (int bb = 0; bb < 8; ++bb) {
      const float* hb = &hx[bb][64 + kq*64 + wh*32];
      float a = 0.f;
      #pragma unroll
      for (int i4 = 0; i4 < 8; ++i4) {
        float4 h4 = *(const float4*)(hb + i4*4);
        a = fmaf(winreg[i4*4+0], h4.x, a);
        a = fmaf(winreg[i4*4+1], h4.y, a);
        a = fmaf(winreg[i4*4+2], h4.z, a);
        a = fmaf(winreg[i4*4+3], h4.w, a);
      }
      if (lane < 60) part[kq][bb][lane] = a;
    }
    __syncthreads();   // J

    // ---- K: finish p = exp(h@winW^T + winb); update kappa ----
    if (tid < 240) {
      int bb = tid / 30, j = tid % 30;
      float s = 0.f;
      #pragma unroll
      for (int q = 0; q < KQ; ++q) s += part[q][bb][j] + part[q][bb][30+j];
      float p = __expf(s + winb_r);
      p_lds[bb][j] = p;
      if (j >= 20) {
        float nk = kap_lds[bb][j-20] + p;
        kap_lds[bb][j-20] = nk;
        if (t == T_-1 && gblk == 0) out[OUT_KAP + (b0+bb)*K_ + (j-20)] = nk;
      }
    }
    __syncthreads();   // L

    // ---- M: fused phi + w-scatter (wave = batch; u = lane) ----
    {
      int bb = kq, u = lane;
      float s = 0.f;
      float uf = (float)u;
      #pragma unroll
      for (int k = 0; k < K_; ++k) {
        float d = kap_lds[bb][k] - uf;
        s += p_lds[bb][k] * __expf(-p_lds[bb][10+k]*d*d);
      }
      float phiv = s * scale_lds[bb];
      atomicAdd(&hx[bb][4 + ids_lds[bb][u]], phiv);   // ds_add_f32, in-wave order
      if (t == T_-1 && gblk == 0) {
        out[OUT_PHI + (b0+bb)*65 + u] = phiv;
        if (tid < 8) {  // u = 64 tail element of phi output
          int b2 = tid;
          float s2 = 0.f;
          #pragma unroll
          for (int k = 0; k < K_; ++k) {
            float d = kap_lds[b2][k] - 64.f;
            s2 += p_lds[b2][k] * __expf(-p_lds[b2][10+k]*d*d);
          }
          out[OUT_PHI + (b0+b2)*65 + 64] = s2 * scale_lds[b2];
        }
      }
    }
    __syncthreads();   // N: scatter complete -> w readable

    // ---- O: rotated ws-store (one WG per step) ----
    if (gblk == (t & 31) && tid < 480) {
      int bb = tid / 60, v = tid % 60;
      float wv = hx[bb][4+v];
      out[OUT_WS + ((long)(b0+bb)*T_ + t)*V_ + v] = wv;
      if (t == T_-1) out[OUT_W + (b0+bb)*V_ + v] = wv;
    }
    // no sync needed: O only reads hx; next A also only reads hx/part-writes own slot
  }
}

extern "C" void kernel_launch(void* const* d_in, const int* in_sizes, int n_in,
                              void* d_out, int out_size, void* d_ws, size_t ws_size,
                              hipStream_t stream) {
  const float* x         = (const float*)d_in[0];
  const float* onehots   = (const float*)d_in[1];
  const float* text_lens = (const float*)d_in[2];
  const float* w_old     = (const float*)d_in[3];
  const float* kappa_old = (const float*)d_in[4];
  const float* prev_h    = (const float*)d_in[5];
  const float* prev_c    = (const float*)d_in[6];
  const float* W_ih      = (const float*)d_in[7];
  const float* W_hh      = (const float*)d_in[8];
  const float* b_ih      = (const float*)d_in[9];
  const float* b_hh      = (const float*)d_in[10];
  const float* win_W     = (const float*)d_in[11];
  const float* win_b     = (const float*)d_in[12];
  float* ws  = (float*)d_ws;
  float* out = (float*)d_out;

  // zero barrier flags (replayed at the head of every graph replay)
  hipMemsetAsync(d_ws, 0, 4096, stream);

  lstm_attn_persistent<<<NWG, NTH, 0, stream>>>(
      x, onehots, text_lens, w_old, kappa_old, prev_h, prev_c,
      W_ih, W_hh, b_ih, b_hh, win_W, win_b, ws, out);
}

// Round 4
// 4391.632 us; speedup vs baseline: 5.4463x; 1.3103x over previous
//
#include <hip/hip_runtime.h>
#include <math.h>

#define B_  64
#define T_  800
#define U_  64
#define V_  60
#define C_  512
#define K_  10
#define KX  576   // padded hx: [0..3]=x(3)+pad, [4..63]=w(60), [64..575]=h(512)
#define NWG 256
#define NTH 512
#define KQ  8     // k-split across the 8 waves of a WG
#define KSL 72    // KX / KQ
#define NB  4     // batches per group
#define GRPWG 16  // WGs per group (16 groups x 16 WGs)

// ws layout: ull hpair[2][B_][C_]  (value lo32, tag hi32) = 512KB, memset each launch
__device__ __forceinline__ float sigm(float v)  { return 1.f/(1.f+__expf(-v)); }
__device__ __forceinline__ float tanhx(float v) { return 1.f - 2.f/(__expf(2.f*v)+1.f); }

__launch_bounds__(NTH, 2)
__global__ void lstm_attn_persistent(
    const float* __restrict__ x,         // [B,T,3]
    const float* __restrict__ onehots,   // [B,U,V]
    const float* __restrict__ text_lens, // [B,1]
    const float* __restrict__ w_old,     // [B,V]
    const float* __restrict__ kappa_old, // [B,K]
    const float* __restrict__ prev_h,    // [B,C]
    const float* __restrict__ prev_c,    // [B,C]
    const float* __restrict__ W_ih,      // [4C, 63]
    const float* __restrict__ W_hh,      // [4C, C]
    const float* __restrict__ b_ih,      // [4C]
    const float* __restrict__ b_hh,      // [4C]
    const float* __restrict__ win_W,     // [30, C]
    const float* __restrict__ win_b,     // [30]
    unsigned long long* __restrict__ hpair,
    float* __restrict__ out)
{
  // out layout (flat, return order)
  const long OUT_WS  = 0;
  const long OUT_HS  = (long)B_*T_*V_;
  const long OUT_H   = OUT_HS + (long)B_*T_*C_;
  const long OUT_C   = OUT_H  + (long)B_*C_;
  const long OUT_W   = OUT_C  + (long)B_*C_;
  const long OUT_KAP = OUT_W  + (long)B_*V_;
  const long OUT_PHI = OUT_KAP+ (long)B_*K_;

  const int tid  = threadIdx.x;
  const int kq   = tid >> 6;        // wave id 0..7 = k-slice
  const int lane = tid & 63;
  const int bid  = blockIdx.x;
  const int grp  = bid & 15;        // group id (4 batches)
  const int gblk = bid >> 4;        // 0..15: 128-gate-col block
  const int b0   = grp * NB;

  __shared__ __align__(16) float hx[NB][KX];          // per-b extended input vector
  __shared__ __align__(16) float part[KQ][NB][2][68]; // k-slice partials (s=col half), padded
  __shared__ float p_lds[NB][32];
  __shared__ float kap_lds[NB][12];
  __shared__ float scale_lds[NB];
  __shared__ int   ids_lds[NB][64];

  // ---- persistent registers ----
  // permuted gate col gp = ch*4 + gate; WG owns gp in [gblk*128, gblk*128+128)
  // lane covers s=0: gp0 = gblk*128+lane, s=1: gp1 = gp0+64
  float Wreg[2][KSL];
  float bias2[2];
  #pragma unroll
  for (int s = 0; s < 2; ++s) {
    int gp   = gblk*128 + lane + 64*s;
    int gate = gp & 3;
    int ch   = gp >> 2;
    int row  = gate*C_ + ch;
    #pragma unroll
    for (int i = 0; i < KSL; ++i) {
      int k = kq*KSL + i;
      float v;
      if      (k < 3)  v = W_ih[row*63 + k];
      else if (k == 3) v = 0.f;
      else if (k < 64) v = W_ih[row*63 + (k-1)];
      else             v = W_hh[row*C_ + (k-64)];
      Wreg[s][i] = v;
    }
    bias2[s] = b_ih[row] + b_hh[row];
  }

  // window rows: lanes 0..59 hold (j=lane%30, half=lane/30), 32-wide k-slice
  const int wj   = lane % 30;
  const int wh   = (lane < 60) ? (lane / 30) : 0;
  float winreg[32];
  #pragma unroll
  for (int i = 0; i < 32; ++i)
    winreg[i] = win_W[wj*C_ + kq*64 + wh*32 + i];

  // LSTM cell state: tid<128 owns (bb = tid>>5, ch = gblk*32 + (tid&31))
  const int ub    = tid >> 5;       // 0..3 when tid<128
  const int chloc = tid & 31;
  const int mych  = gblk*32 + chloc;
  float c_reg = 0.f;
  if (tid < 128) c_reg = prev_c[(long)(b0 + ub)*C_ + mych];

  float winb_r = (tid < 120) ? win_b[tid % 30] : 0.f;

  // ---- preamble staging ----
  for (int i = tid; i < NB*KX; i += NTH) {
    int bb = i / KX, k = i % KX;
    int b = b0 + bb;
    float v;
    if      (k < 3)  v = x[((long)b*T_ + 0)*3 + k];
    else if (k < 4)  v = 0.f;
    else if (k < 64) v = w_old[b*V_ + (k-4)];
    else             v = prev_h[(long)b*C_ + (k-64)];
    hx[bb][k] = v;
  }
  for (int i = tid; i < NB*K_; i += NTH)
    kap_lds[i/K_][i%K_] = kappa_old[(b0 + i/K_)*K_ + i%K_];
  if (tid < NB) scale_lds[tid] = (float)U_ / text_lens[b0 + tid];
  for (int i = tid; i < NB*U_; i += NTH) {          // one-hot -> char id
    int bb = i / U_, u = i % U_;
    const float* oh = onehots + ((long)(b0+bb)*U_ + u)*V_;
    int best = 0; float bv = oh[0];
    for (int vv = 1; vv < V_; ++vv) { float q = oh[vv]; if (q > bv) { bv = q; best = vv; } }
    ids_lds[bb][u] = best;
  }
  __syncthreads();

  for (int t = 0; t < T_; ++t) {
    // ---- A: gates GEMM (k-split over waves; 2 cols/lane; hx broadcast) ----
    float acc[NB][2];
    #pragma unroll
    for (int bb = 0; bb < NB; ++bb) {
      acc[bb][0] = (kq == 0) ? bias2[0] : 0.f;
      acc[bb][1] = (kq == 0) ? bias2[1] : 0.f;
    }
    #pragma unroll
    for (int bb = 0; bb < NB; ++bb) {
      const float* hxb = &hx[bb][kq*KSL];
      float a0 = acc[bb][0], a1 = acc[bb][1];
      #pragma unroll
      for (int i4 = 0; i4 < KSL/4; ++i4) {
        float4 h4 = *(const float4*)(hxb + i4*4);
        a0 = fmaf(Wreg[0][i4*4+0], h4.x, a0);
        a0 = fmaf(Wreg[0][i4*4+1], h4.y, a0);
        a0 = fmaf(Wreg[0][i4*4+2], h4.z, a0);
        a0 = fmaf(Wreg[0][i4*4+3], h4.w, a0);
        a1 = fmaf(Wreg[1][i4*4+0], h4.x, a1);
        a1 = fmaf(Wreg[1][i4*4+1], h4.y, a1);
        a1 = fmaf(Wreg[1][i4*4+2], h4.z, a1);
        a1 = fmaf(Wreg[1][i4*4+3], h4.w, a1);
      }
      acc[bb][0] = a0; acc[bb][1] = a1;
    }
    #pragma unroll
    for (int bb = 0; bb < NB; ++bb) {
      part[kq][bb][0][lane] = acc[bb][0];
      part[kq][bb][1][lane] = acc[bb][1];
    }
    __syncthreads();   // B

    // ---- C: cell update + fused (h,tag) publish | zero w-slots | stage x(t+1) ----
    if (tid < 128) {
      // cols for channel mych: gp=4*mych+gate -> s = chloc>>4, lane4 = (chloc&15)*4
      const int sr = chloc >> 4, c4 = (chloc & 15) * 4;
      float4 s = make_float4(0.f, 0.f, 0.f, 0.f);
      #pragma unroll
      for (int q = 0; q < KQ; ++q) {
        float4 v = *(const float4*)&part[q][ub][sr][c4];
        s.x += v.x; s.y += v.y; s.z += v.z; s.w += v.w;
      }
      float ig = sigm(s.x), fg = sigm(s.y), gg = tanhx(s.z), og = sigm(s.w);
      float c = fg*c_reg + ig*gg;
      c_reg = c;
      float h = og * tanhx(c);
      int b = b0 + ub;
      unsigned long long pk =
          ((unsigned long long)(unsigned)(t+1) << 32) | (unsigned long long)__float_as_uint(h);
      __hip_atomic_store(&hpair[(long)(t&1)*B_*C_ + (long)b*C_ + mych], pk,
                         __ATOMIC_RELAXED, __HIP_MEMORY_SCOPE_AGENT);
      out[OUT_HS + ((long)b*T_ + t)*C_ + mych] = h;
      if (t == T_-1) {
        out[OUT_H + (long)b*C_ + mych] = h;
        out[OUT_C + (long)b*C_ + mych] = c;
      }
    } else if (tid < 368) {
      int s0 = tid - 128;                 // zero 240 w-slots
      hx[s0/60][4 + s0%60] = 0.f;
    } else if (tid < 384) {
      int i = tid - 368, bb = i >> 2, k = i & 3;
      int tn = t + 1;
      hx[bb][k] = (k < 3 && tn < T_) ? x[((long)(b0+bb)*T_ + tn)*3 + k] : 0.f;
    }
    // no sync: G touches disjoint LDS (hx h-region), gated by data-dependency poll

    // ---- G: poll-gather fused (h,tag) pairs -> hx h-region ----
    {
      const unsigned long long* src = hpair + (long)(t&1)*B_*C_;
      const long base = (long)b0*C_ + tid*4;
      const int want = t + 1;
      unsigned long long v0, v1, v2, v3;
      while (true) {
        v0 = __hip_atomic_load(&src[base+0], __ATOMIC_RELAXED, __HIP_MEMORY_SCOPE_AGENT);
        v1 = __hip_atomic_load(&src[base+1], __ATOMIC_RELAXED, __HIP_MEMORY_SCOPE_AGENT);
        v2 = __hip_atomic_load(&src[base+2], __ATOMIC_RELAXED, __HIP_MEMORY_SCOPE_AGENT);
        v3 = __hip_atomic_load(&src[base+3], __ATOMIC_RELAXED, __HIP_MEMORY_SCOPE_AGENT);
        if ((int)(v0 >> 32) >= want && (int)(v1 >> 32) >= want &&
            (int)(v2 >> 32) >= want && (int)(v3 >> 32) >= want) break;
      }
      int off = tid * 4;
      int bb = off >> 9, k = off & 511;
      *(float4*)&hx[bb][64 + k] = make_float4(
          __uint_as_float((unsigned)v0), __uint_as_float((unsigned)v1),
          __uint_as_float((unsigned)v2), __uint_as_float((unsigned)v3));
    }
    __syncthreads();   // H

    // ---- I: window projection partials (lanes 0..59) ----
    #pragma unroll
    for (int bb = 0; bb < NB; ++bb) {
      const float* hb = &hx[bb][64 + kq*64 + wh*32];
      float a = 0.f;
      #pragma unroll
      for (int i4 = 0; i4 < 8; ++i4) {
        float4 h4 = *(const float4*)(hb + i4*4);
        a = fmaf(winreg[i4*4+0], h4.x, a);
        a = fmaf(winreg[i4*4+1], h4.y, a);
        a = fmaf(winreg[i4*4+2], h4.z, a);
        a = fmaf(winreg[i4*4+3], h4.w, a);
      }
      if (lane < 60) part[kq][bb][0][lane] = a;
    }
    __syncthreads();   // J

    // ---- K: finish p = exp(h@winW^T + winb); update kappa ----
    if (tid < 120) {
      int bb = tid / 30, j = tid % 30;
      float s = 0.f;
      #pragma unroll
      for (int q = 0; q < KQ; ++q) s += part[q][bb][0][j] + part[q][bb][0][30+j];
      float p = __expf(s + winb_r);
      p_lds[bb][j] = p;
      if (j >= 20) {
        float nk = kap_lds[bb][j-20] + p;
        kap_lds[bb][j-20] = nk;
        if (t == T_-1 && gblk == 0) out[OUT_KAP + (b0+bb)*K_ + (j-20)] = nk;
      }
    }
    __syncthreads();   // L

    // ---- M: fused phi + w-scatter (wave = batch; u = lane) ----
    if (kq < NB) {
      int bb = kq, u = lane;
      float s = 0.f;
      float uf = (float)u;
      #pragma unroll
      for (int k = 0; k < K_; ++k) {
        float d = kap_lds[bb][k] - uf;
        s += p_lds[bb][k] * __expf(-p_lds[bb][10+k]*d*d);
      }
      float phiv = s * scale_lds[bb];
      atomicAdd(&hx[bb][4 + ids_lds[bb][u]], phiv);   // ds_add_f32, in-wave order
      if (t == T_-1 && gblk == 0) out[OUT_PHI + (b0+bb)*65 + u] = phiv;
    }
    if (t == T_-1 && gblk == 0 && tid < NB) {         // u = 64 tail of phi output
      int b2 = tid;
      float s2 = 0.f;
      #pragma unroll
      for (int k = 0; k < K_; ++k) {
        float d = kap_lds[b2][k] - 64.f;
        s2 += p_lds[b2][k] * __expf(-p_lds[b2][10+k]*d*d);
      }
      out[OUT_PHI + (b0+b2)*65 + 64] = s2 * scale_lds[b2];
    }
    __syncthreads();   // N: scatter complete -> w readable

    // ---- O: rotated ws-store (one WG of the group per step) ----
    if (gblk == (t & 15) && tid < 240) {
      int bb = tid / 60, v = tid % 60;
      float wv = hx[bb][4+v];
      out[OUT_WS + ((long)(b0+bb)*T_ + t)*V_ + v] = wv;
      if (t == T_-1) out[OUT_W + (b0+bb)*V_ + v] = wv;
    }
    // no sync: O and next-A only read hx; first write is next-C (post-B sync)
  }
}

extern "C" void kernel_launch(void* const* d_in, const int* in_sizes, int n_in,
                              void* d_out, int out_size, void* d_ws, size_t ws_size,
                              hipStream_t stream) {
  const float* x         = (const float*)d_in[0];
  const float* onehots   = (const float*)d_in[1];
  const float* text_lens = (const float*)d_in[2];
  const float* w_old     = (const float*)d_in[3];
  const float* kappa_old = (const float*)d_in[4];
  const float* prev_h    = (const float*)d_in[5];
  const float* prev_c    = (const float*)d_in[6];
  const float* W_ih      = (const float*)d_in[7];
  const float* W_hh      = (const float*)d_in[8];
  const float* b_ih      = (const float*)d_in[9];
  const float* b_hh      = (const float*)d_in[10];
  const float* win_W     = (const float*)d_in[11];
  const float* win_b     = (const float*)d_in[12];
  unsigned long long* hpair = (unsigned long long*)d_ws;
  float* out = (float*)d_out;

  // zero the (h,tag) pair region (tags must start below 1; replay leaves stale tags)
  hipMemsetAsync(d_ws, 0, 2ull*B_*C_*sizeof(unsigned long long), stream);

  lstm_attn_persistent<<<NWG, NTH, 0, stream>>>(
      x, onehots, text_lens, w_old, kappa_old, prev_h, prev_c,
      W_ih, W_hh, b_ih, b_hh, win_W, win_b, hpair, out);
}